// Round 11
// baseline (112.992 us; speedup 1.0000x reference)
//
#include <hip/hip_runtime.h>

#define K_RECENT 10

typedef float          f32x4 __attribute__((ext_vector_type(4)));
typedef int            i32x4 __attribute__((ext_vector_type(4)));
typedef unsigned short u16x8 __attribute__((ext_vector_type(8)));

// ---------------------------------------------------------------------------
// Kernel 1: user_pref[b, :] = masked mean of region_emb over last-10 valid
// positions. One block per b, 128 threads (= D).
// ---------------------------------------------------------------------------
__global__ void pref_kernel(const int* __restrict__ user_seq,
                            const int* __restrict__ user_seq_len,
                            const int* __restrict__ poi_region_id,
                            const float* __restrict__ region_emb,
                            float* __restrict__ pref,
                            int S, int D) {
    int b = blockIdx.x;
    int tid = threadIdx.x;
    __shared__ int rids[K_RECENT];

    int len = user_seq_len[b];
    if (tid < K_RECENT) {
        int pos = len - K_RECENT + tid;
        int r = -1;
        if (pos >= 0) {
            int poi = user_seq[b * S + pos];
            r = poi_region_id[poi];
        }
        rids[tid] = r;
    }
    __syncthreads();

    float acc = 0.f;
    int cnt = 0;
#pragma unroll
    for (int j = 0; j < K_RECENT; ++j) {
        int r = rids[j];
        if (r >= 0) {
            ++cnt;
            acc += region_emb[r * D + tid];
        }
    }
    float c = (cnt > 0) ? (float)cnt : 1.f;
    pref[b * D + tid] = acc / c;
}

// ---------------------------------------------------------------------------
// Kernel 2 (proven BT=8): scores[b,r] = alpha * (pref[b] . region_emb[r])
// ---------------------------------------------------------------------------
__global__ void scores_kernel(const float* __restrict__ pref,
                              const float* __restrict__ region_emb,
                              const float* __restrict__ alpha_p,
                              float* __restrict__ scores,
                              int R) {
    const int BT = 8;
    const int D  = 128;
    __shared__ float pl[BT * D];

    int tid = threadIdx.x;
    int b0  = blockIdx.y * BT;
    float alpha = alpha_p[0];

    ((f32x4*)pl)[tid] = ((const f32x4*)(pref + (size_t)b0 * D))[tid];
    __syncthreads();

    int r = blockIdx.x * blockDim.x + tid;
    if (r >= R) return;

    float acc[BT];
#pragma unroll
    for (int bb = 0; bb < BT; ++bb) acc[bb] = 0.f;

    const f32x4* erow = (const f32x4*)(region_emb + (size_t)r * D);
#pragma unroll 8
    for (int d4 = 0; d4 < D / 4; ++d4) {
        f32x4 e = erow[d4];
#pragma unroll
        for (int bb = 0; bb < BT; ++bb) {
            f32x4 pv = *reinterpret_cast<const f32x4*>(&pl[bb * D + d4 * 4]);
            acc[bb] = fmaf(e.x, pv.x,
                      fmaf(e.y, pv.y,
                      fmaf(e.z, pv.z,
                      fmaf(e.w, pv.w, acc[bb]))));
        }
    }
#pragma unroll
    for (int bb = 0; bb < BT; ++bb)
        scores[(size_t)(b0 + bb) * R + r] = acc[bb] * alpha;
}

// ---------------------------------------------------------------------------
// rid -> uint16 (R <= 2048 < 65536). One-time 0.3 MB conversion.
// ---------------------------------------------------------------------------
__global__ void rid16_kernel(const int* __restrict__ rid,
                             unsigned short* __restrict__ rid16, int L) {
    int i = blockIdx.x * blockDim.x + threadIdx.x;
    int i4 = i * 4;
    if (i4 + 3 < L) {
        i32x4 v = *(const i32x4*)(rid + i4);
        rid16[i4 + 0] = (unsigned short)v.x;
        rid16[i4 + 1] = (unsigned short)v.y;
        rid16[i4 + 2] = (unsigned short)v.z;
        rid16[i4 + 3] = (unsigned short)v.w;
    } else {
        for (int k = i4; k < L; ++k) rid16[k] = (unsigned short)rid[k];
    }
}

// ---------------------------------------------------------------------------
// Kernel 3 (u16 rid): out[b,l] = pred[b,l] + srow[rid16[l]]  (alpha folded)
// f32x8 granularity: one ushort8 (16 B) feeds 2 f32x4 pred loads + 2 nt
// stores. Halves rid L2 bytes and rid load-instruction count vs int32.
// nt stores load-bearing (round-9 A/B: plain stores +22 us).
// ---------------------------------------------------------------------------
#define OUT_BLOCK   256
#define OUT_F       4
#define PIPE        4
#define MAX_R       2048

__global__ void out_kernel_u16(const float* __restrict__ pred,
                               const float* __restrict__ scores,
                               const unsigned short* __restrict__ rid16,
                               float* __restrict__ out,
                               int L8, int L, int R, int CPB8) {
    __shared__ float srow[MAX_R];
    int b   = blockIdx.y;
    int tid = threadIdx.x;

    const float* g = scores + (size_t)b * R;
    int R4 = R >> 2;
    for (int i = tid; i < R4; i += OUT_BLOCK)
        ((f32x4*)srow)[i] = ((const f32x4*)g)[i];
    for (int i = (R4 << 2) + tid; i < R; i += OUT_BLOCK)
        srow[i] = g[i];
    __syncthreads();

    int base = blockIdx.x * CPB8;            // f32x8 units
    int n = min(CPB8, L8 - base);
    if (n <= 0) return;

    const u16x8* rp = (const u16x8*)rid16 + base;
    const f32x4* pp = (const f32x4*)(pred + (size_t)b * L) + 2 * (size_t)base;
    f32x4*       op = (f32x4*)(out + (size_t)b * L) + 2 * (size_t)base;

    int rounds  = n >> 8;
    int batches = rounds / PIPE;

    for (int kb = 0; kb < batches; ++kb) {
        int i0 = kb * (PIPE * OUT_BLOCK) + tid;
        u16x8 c[PIPE];
        f32x4 pa[PIPE], pb[PIPE];
#pragma unroll
        for (int j = 0; j < PIPE; ++j) c[j] = rp[i0 + j * OUT_BLOCK];
#pragma unroll
        for (int j = 0; j < PIPE; ++j) {
            int i2 = 2 * (i0 + j * OUT_BLOCK);
            pa[j] = pp[i2];
            pb[j] = pp[i2 + 1];
        }
#pragma unroll
        for (int j = 0; j < PIPE; ++j) {
            int i2 = 2 * (i0 + j * OUT_BLOCK);
            f32x4 oa, ob;
            oa.x = pa[j].x + srow[c[j][0]];
            oa.y = pa[j].y + srow[c[j][1]];
            oa.z = pa[j].z + srow[c[j][2]];
            oa.w = pa[j].w + srow[c[j][3]];
            ob.x = pb[j].x + srow[c[j][4]];
            ob.y = pb[j].y + srow[c[j][5]];
            ob.z = pb[j].z + srow[c[j][6]];
            ob.w = pb[j].w + srow[c[j][7]];
            __builtin_nontemporal_store(oa, &op[i2]);
            __builtin_nontemporal_store(ob, &op[i2 + 1]);
        }
    }
    for (int k = batches * PIPE; k < rounds; ++k) {
        int i = k * OUT_BLOCK + tid;
        u16x8 c = rp[i];
        int i2 = 2 * i;
        f32x4 pa = pp[i2], pb = pp[i2 + 1];
        f32x4 oa, ob;
        oa.x = pa.x + srow[c[0]]; oa.y = pa.y + srow[c[1]];
        oa.z = pa.z + srow[c[2]]; oa.w = pa.w + srow[c[3]];
        ob.x = pb.x + srow[c[4]]; ob.y = pb.y + srow[c[5]];
        ob.z = pb.z + srow[c[6]]; ob.w = pb.w + srow[c[7]];
        __builtin_nontemporal_store(oa, &op[i2]);
        __builtin_nontemporal_store(ob, &op[i2 + 1]);
    }
    int i = rounds * OUT_BLOCK + tid;
    if (i < n) {
        u16x8 c = rp[i];
        int i2 = 2 * i;
        f32x4 pa = pp[i2], pb = pp[i2 + 1];
        f32x4 oa, ob;
        oa.x = pa.x + srow[c[0]]; oa.y = pa.y + srow[c[1]];
        oa.z = pa.z + srow[c[2]]; oa.w = pa.w + srow[c[3]];
        ob.x = pb.x + srow[c[4]]; ob.y = pb.y + srow[c[5]];
        ob.z = pb.z + srow[c[6]]; ob.w = pb.w + srow[c[7]];
        __builtin_nontemporal_store(oa, &op[i2]);
        __builtin_nontemporal_store(ob, &op[i2 + 1]);
    }
}

// ---------------------------------------------------------------------------
// Proven round-8 int-rid pipe kernel (fallback if ws can't hold rid16).
// ---------------------------------------------------------------------------
__global__ void out_kernel_pipe(const float* __restrict__ pred,
                                const float* __restrict__ scores,
                                const int* __restrict__ rid,
                                float* __restrict__ out,
                                int L4, int L, int R, int CPB) {
    __shared__ float srow[MAX_R];
    int b   = blockIdx.y;
    int tid = threadIdx.x;

    const float* g = scores + (size_t)b * R;
    int R4 = R >> 2;
    for (int i = tid; i < R4; i += OUT_BLOCK)
        ((f32x4*)srow)[i] = ((const f32x4*)g)[i];
    for (int i = (R4 << 2) + tid; i < R; i += OUT_BLOCK)
        srow[i] = g[i];
    __syncthreads();

    int base = blockIdx.x * CPB;
    int n = min(CPB, L4 - base);
    if (n <= 0) return;

    const i32x4* rp = (const i32x4*)rid + base;
    const f32x4* pp = (const f32x4*)(pred + (size_t)b * L) + base;
    f32x4*       op = (f32x4*)(out + (size_t)b * L) + base;

    int rounds  = n >> 8;
    int batches = rounds / PIPE;

    for (int kb = 0; kb < batches; ++kb) {
        int i0 = kb * (PIPE * OUT_BLOCK) + tid;
        i32x4 r4v[PIPE];
        f32x4 p[PIPE];
#pragma unroll
        for (int j = 0; j < PIPE; ++j) r4v[j] = rp[i0 + j * OUT_BLOCK];
#pragma unroll
        for (int j = 0; j < PIPE; ++j) p[j]  = pp[i0 + j * OUT_BLOCK];
#pragma unroll
        for (int j = 0; j < PIPE; ++j) {
            f32x4 o;
            o.x = p[j].x + srow[r4v[j].x];
            o.y = p[j].y + srow[r4v[j].y];
            o.z = p[j].z + srow[r4v[j].z];
            o.w = p[j].w + srow[r4v[j].w];
            __builtin_nontemporal_store(o, &op[i0 + j * OUT_BLOCK]);
        }
    }
    for (int k = batches * PIPE; k < rounds; ++k) {
        int i = k * OUT_BLOCK + tid;
        i32x4 c = rp[i];
        f32x4 p = pp[i];
        f32x4 o;
        o.x = p.x + srow[c.x];
        o.y = p.y + srow[c.y];
        o.z = p.z + srow[c.z];
        o.w = p.w + srow[c.w];
        __builtin_nontemporal_store(o, &op[i]);
    }
    int i = rounds * OUT_BLOCK + tid;
    if (i < n) {
        i32x4 c = rp[i];
        f32x4 p = pp[i];
        f32x4 o;
        o.x = p.x + srow[c.x];
        o.y = p.y + srow[c.y];
        o.z = p.z + srow[c.z];
        o.w = p.w + srow[c.w];
        __builtin_nontemporal_store(o, &op[i]);
    }
}

__global__ void out_kernel_scalar(const float* __restrict__ pred,
                                  const float* __restrict__ scores,
                                  const int* __restrict__ rid,
                                  float* __restrict__ out,
                                  int l0, int L, int R) {
    int b = blockIdx.y;
    int l = l0 + blockIdx.x * blockDim.x + threadIdx.x;
    if (l >= L) return;
    out[(size_t)b * L + l] =
        pred[(size_t)b * L + l] + scores[(size_t)b * R + rid[l]];
}

extern "C" void kernel_launch(void* const* d_in, const int* in_sizes, int n_in,
                              void* d_out, int out_size, void* d_ws, size_t ws_size,
                              hipStream_t stream) {
    const float* pred_base     = (const float*)d_in[0];
    const int*   user_seq      = (const int*)d_in[1];
    const int*   user_seq_len  = (const int*)d_in[2];
    const int*   poi_region_id = (const int*)d_in[3];
    const float* region_emb    = (const float*)d_in[4];
    const float* alpha         = (const float*)d_in[5];
    float*       out           = (float*)d_out;

    const int B = in_sizes[2];              // 1024
    const int S = in_sizes[1] / B;          // 200
    const int L = in_sizes[3];              // 50000
    const int D = 128;
    const int R = in_sizes[4] / D;          // 2000

    // Workspace: scores [B*R] f32, pref [B*D] f32, rid16 [L] u16
    size_t scores_b = (size_t)B * R * sizeof(float);
    size_t pref_b   = (size_t)B * D * sizeof(float);
    float* scores = (float*)d_ws;
    float* pref   = (float*)((char*)d_ws + scores_b);
    unsigned short* rid16 = (unsigned short*)((char*)d_ws + scores_b + pref_b);
    bool have_rid16 = ws_size >= scores_b + pref_b + (size_t)L * 2;

    // 1) user_pref
    pref_kernel<<<B, D, 0, stream>>>(user_seq, user_seq_len, poi_region_id,
                                     region_emb, pref, S, D);

    // 2) scores[B,R] (alpha folded in)
    dim3 g2((R + 255) / 256, B / 8);
    scores_kernel<<<g2, 256, 0, stream>>>(pref, region_emb, alpha, scores, R);

    // 2b) rid16 conversion
    if (have_rid16 && R <= MAX_R) {
        int nq = (L + 3) / 4;
        rid16_kernel<<<(nq + 255) / 256, 256, 0, stream>>>(poi_region_id, rid16, L);
    }

    // 3) output
    int L8 = L / 8;
    int L4 = L / 4;
    if (have_rid16 && R <= MAX_R && L8 > 0) {
        int CPB8 = (L8 + OUT_F - 1) / OUT_F;
        dim3 g3(OUT_F, B);
        out_kernel_u16<<<g3, OUT_BLOCK, 0, stream>>>(
            pred_base, scores, rid16, out, L8, L, R, CPB8);
        int tail = L - L8 * 8;
        if (tail > 0) {
            dim3 gt(1, B);
            out_kernel_scalar<<<gt, 64, 0, stream>>>(
                pred_base, scores, poi_region_id, out, L8 * 8, L, R);
        }
    } else if (R <= MAX_R && L4 > 0) {
        int CPB = (L4 + OUT_F - 1) / OUT_F;
        dim3 g3(OUT_F, B);
        out_kernel_pipe<<<g3, OUT_BLOCK, 0, stream>>>(
            pred_base, scores, poi_region_id, out, L4, L, R, CPB);
        int tail = L - L4 * 4;
        if (tail > 0) {
            dim3 gt(1, B);
            out_kernel_scalar<<<gt, 64, 0, stream>>>(
                pred_base, scores, poi_region_id, out, L4 * 4, L, R);
        }
    } else {
        dim3 gt((L + 255) / 256, B);
        out_kernel_scalar<<<gt, 256, 0, stream>>>(
            pred_base, scores, poi_region_id, out, 0, L, R);
    }
}

// Round 12
// 98.673 us; speedup vs baseline: 1.1451x; 1.1451x over previous
//
#include <hip/hip_runtime.h>

#define K_RECENT 10

typedef float          f32x4 __attribute__((ext_vector_type(4)));
typedef int            i32x4 __attribute__((ext_vector_type(4)));
typedef unsigned short u16x4 __attribute__((ext_vector_type(4)));

// ---------------------------------------------------------------------------
// Kernel 1: user_pref[b, :] = masked mean of region_emb over last-10 valid
// positions. One block per b, 128 threads (= D).
// ---------------------------------------------------------------------------
__global__ void pref_kernel(const int* __restrict__ user_seq,
                            const int* __restrict__ user_seq_len,
                            const int* __restrict__ poi_region_id,
                            const float* __restrict__ region_emb,
                            float* __restrict__ pref,
                            int S, int D) {
    int b = blockIdx.x;
    int tid = threadIdx.x;
    __shared__ int rids[K_RECENT];

    int len = user_seq_len[b];
    if (tid < K_RECENT) {
        int pos = len - K_RECENT + tid;
        int r = -1;
        if (pos >= 0) {
            int poi = user_seq[b * S + pos];
            r = poi_region_id[poi];
        }
        rids[tid] = r;
    }
    __syncthreads();

    float acc = 0.f;
    int cnt = 0;
#pragma unroll
    for (int j = 0; j < K_RECENT; ++j) {
        int r = rids[j];
        if (r >= 0) {
            ++cnt;
            acc += region_emb[r * D + tid];
        }
    }
    float c = (cnt > 0) ? (float)cnt : 1.f;
    pref[b * D + tid] = acc / c;
}

// ---------------------------------------------------------------------------
// Kernel 2 (proven BT=8): scores[b,r] = alpha * (pref[b] . region_emb[r])
// ---------------------------------------------------------------------------
__global__ void scores_kernel(const float* __restrict__ pref,
                              const float* __restrict__ region_emb,
                              const float* __restrict__ alpha_p,
                              float* __restrict__ scores,
                              int R) {
    const int BT = 8;
    const int D  = 128;
    __shared__ float pl[BT * D];

    int tid = threadIdx.x;
    int b0  = blockIdx.y * BT;
    float alpha = alpha_p[0];

    ((f32x4*)pl)[tid] = ((const f32x4*)(pref + (size_t)b0 * D))[tid];
    __syncthreads();

    int r = blockIdx.x * blockDim.x + tid;
    if (r >= R) return;

    float acc[BT];
#pragma unroll
    for (int bb = 0; bb < BT; ++bb) acc[bb] = 0.f;

    const f32x4* erow = (const f32x4*)(region_emb + (size_t)r * D);
#pragma unroll 8
    for (int d4 = 0; d4 < D / 4; ++d4) {
        f32x4 e = erow[d4];
#pragma unroll
        for (int bb = 0; bb < BT; ++bb) {
            f32x4 pv = *reinterpret_cast<const f32x4*>(&pl[bb * D + d4 * 4]);
            acc[bb] = fmaf(e.x, pv.x,
                      fmaf(e.y, pv.y,
                      fmaf(e.z, pv.z,
                      fmaf(e.w, pv.w, acc[bb]))));
        }
    }
#pragma unroll
    for (int bb = 0; bb < BT; ++bb)
        scores[(size_t)(b0 + bb) * R + r] = acc[bb] * alpha;
}

// ---------------------------------------------------------------------------
// rid -> uint16 (R <= 2048 < 65536). One-time ~0.3 MB conversion.
// ---------------------------------------------------------------------------
__global__ void rid16_kernel(const int* __restrict__ rid,
                             unsigned short* __restrict__ rid16, int L) {
    int i = blockIdx.x * blockDim.x + threadIdx.x;
    int i4 = i * 4;
    if (i4 + 3 < L) {
        i32x4 v = *(const i32x4*)(rid + i4);
        u16x4 w;
        w.x = (unsigned short)v.x; w.y = (unsigned short)v.y;
        w.z = (unsigned short)v.z; w.w = (unsigned short)v.w;
        *(u16x4*)(rid16 + i4) = w;
    } else {
        for (int k = i4; k < L; ++k) rid16[k] = (unsigned short)rid[k];
    }
}

// ---------------------------------------------------------------------------
// Kernel 3: out[b,l] = pred[b,l] + srow[rid16[l]]   (alpha pre-folded)
// EXACT round-8 proven pipe structure (4 consecutive floats per thread,
// fully-contiguous wave loads/stores, nt stores) — only the rid load is
// narrowed to ushort4 (8 B/lane, still one coalesced 512 B wave run).
// Round-11 lesson: f32x8-per-thread mapping fragmented stores to 32 B
// stride -> +25% WRITE_SIZE; this keeps the mapping, shrinks only rid.
// ---------------------------------------------------------------------------
#define OUT_BLOCK   256
#define OUT_F       4
#define PIPE        4
#define MAX_R       2048

__global__ void out_kernel_u16c(const float* __restrict__ pred,
                                const float* __restrict__ scores,
                                const unsigned short* __restrict__ rid16,
                                float* __restrict__ out,
                                int L4, int L, int R, int CPB) {
    __shared__ float srow[MAX_R];
    int b   = blockIdx.y;
    int tid = threadIdx.x;

    const float* g = scores + (size_t)b * R;
    int R4 = R >> 2;
    for (int i = tid; i < R4; i += OUT_BLOCK)
        ((f32x4*)srow)[i] = ((const f32x4*)g)[i];
    for (int i = (R4 << 2) + tid; i < R; i += OUT_BLOCK)
        srow[i] = g[i];
    __syncthreads();

    int base = blockIdx.x * CPB;
    int n = min(CPB, L4 - base);
    if (n <= 0) return;

    const u16x4* rp = (const u16x4*)rid16 + base;
    const f32x4* pp = (const f32x4*)(pred + (size_t)b * L) + base;
    f32x4*       op = (f32x4*)(out + (size_t)b * L) + base;

    int rounds  = n >> 8;
    int batches = rounds / PIPE;

    for (int kb = 0; kb < batches; ++kb) {
        int i0 = kb * (PIPE * OUT_BLOCK) + tid;
        u16x4 c[PIPE];
        f32x4 p[PIPE];
#pragma unroll
        for (int j = 0; j < PIPE; ++j) c[j] = rp[i0 + j * OUT_BLOCK];
#pragma unroll
        for (int j = 0; j < PIPE; ++j) p[j] = pp[i0 + j * OUT_BLOCK];
#pragma unroll
        for (int j = 0; j < PIPE; ++j) {
            f32x4 o;
            o.x = p[j].x + srow[c[j].x];
            o.y = p[j].y + srow[c[j].y];
            o.z = p[j].z + srow[c[j].z];
            o.w = p[j].w + srow[c[j].w];
            __builtin_nontemporal_store(o, &op[i0 + j * OUT_BLOCK]);
        }
    }
    for (int k = batches * PIPE; k < rounds; ++k) {
        int i = k * OUT_BLOCK + tid;
        u16x4 c = rp[i];
        f32x4 p = pp[i];
        f32x4 o;
        o.x = p.x + srow[c.x];
        o.y = p.y + srow[c.y];
        o.z = p.z + srow[c.z];
        o.w = p.w + srow[c.w];
        __builtin_nontemporal_store(o, &op[i]);
    }
    int i = rounds * OUT_BLOCK + tid;
    if (i < n) {
        u16x4 c = rp[i];
        f32x4 p = pp[i];
        f32x4 o;
        o.x = p.x + srow[c.x];
        o.y = p.y + srow[c.y];
        o.z = p.z + srow[c.z];
        o.w = p.w + srow[c.w];
        __builtin_nontemporal_store(o, &op[i]);
    }
}

// ---------------------------------------------------------------------------
// Proven round-8 int-rid pipe kernel (fallback if ws can't hold rid16).
// ---------------------------------------------------------------------------
__global__ void out_kernel_pipe(const float* __restrict__ pred,
                                const float* __restrict__ scores,
                                const int* __restrict__ rid,
                                float* __restrict__ out,
                                int L4, int L, int R, int CPB) {
    __shared__ float srow[MAX_R];
    int b   = blockIdx.y;
    int tid = threadIdx.x;

    const float* g = scores + (size_t)b * R;
    int R4 = R >> 2;
    for (int i = tid; i < R4; i += OUT_BLOCK)
        ((f32x4*)srow)[i] = ((const f32x4*)g)[i];
    for (int i = (R4 << 2) + tid; i < R; i += OUT_BLOCK)
        srow[i] = g[i];
    __syncthreads();

    int base = blockIdx.x * CPB;
    int n = min(CPB, L4 - base);
    if (n <= 0) return;

    const i32x4* rp = (const i32x4*)rid + base;
    const f32x4* pp = (const f32x4*)(pred + (size_t)b * L) + base;
    f32x4*       op = (f32x4*)(out + (size_t)b * L) + base;

    int rounds  = n >> 8;
    int batches = rounds / PIPE;

    for (int kb = 0; kb < batches; ++kb) {
        int i0 = kb * (PIPE * OUT_BLOCK) + tid;
        i32x4 r4v[PIPE];
        f32x4 p[PIPE];
#pragma unroll
        for (int j = 0; j < PIPE; ++j) r4v[j] = rp[i0 + j * OUT_BLOCK];
#pragma unroll
        for (int j = 0; j < PIPE; ++j) p[j]  = pp[i0 + j * OUT_BLOCK];
#pragma unroll
        for (int j = 0; j < PIPE; ++j) {
            f32x4 o;
            o.x = p[j].x + srow[r4v[j].x];
            o.y = p[j].y + srow[r4v[j].y];
            o.z = p[j].z + srow[r4v[j].z];
            o.w = p[j].w + srow[r4v[j].w];
            __builtin_nontemporal_store(o, &op[i0 + j * OUT_BLOCK]);
        }
    }
    for (int k = batches * PIPE; k < rounds; ++k) {
        int i = k * OUT_BLOCK + tid;
        i32x4 c = rp[i];
        f32x4 p = pp[i];
        f32x4 o;
        o.x = p.x + srow[c.x];
        o.y = p.y + srow[c.y];
        o.z = p.z + srow[c.z];
        o.w = p.w + srow[c.w];
        __builtin_nontemporal_store(o, &op[i]);
    }
    int i = rounds * OUT_BLOCK + tid;
    if (i < n) {
        i32x4 c = rp[i];
        f32x4 p = pp[i];
        f32x4 o;
        o.x = p.x + srow[c.x];
        o.y = p.y + srow[c.y];
        o.z = p.z + srow[c.z];
        o.w = p.w + srow[c.w];
        __builtin_nontemporal_store(o, &op[i]);
    }
}

__global__ void out_kernel_scalar(const float* __restrict__ pred,
                                  const float* __restrict__ scores,
                                  const int* __restrict__ rid,
                                  float* __restrict__ out,
                                  int l0, int L, int R) {
    int b = blockIdx.y;
    int l = l0 + blockIdx.x * blockDim.x + threadIdx.x;
    if (l >= L) return;
    out[(size_t)b * L + l] =
        pred[(size_t)b * L + l] + scores[(size_t)b * R + rid[l]];
}

extern "C" void kernel_launch(void* const* d_in, const int* in_sizes, int n_in,
                              void* d_out, int out_size, void* d_ws, size_t ws_size,
                              hipStream_t stream) {
    const float* pred_base     = (const float*)d_in[0];
    const int*   user_seq      = (const int*)d_in[1];
    const int*   user_seq_len  = (const int*)d_in[2];
    const int*   poi_region_id = (const int*)d_in[3];
    const float* region_emb    = (const float*)d_in[4];
    const float* alpha         = (const float*)d_in[5];
    float*       out           = (float*)d_out;

    const int B = in_sizes[2];              // 1024
    const int S = in_sizes[1] / B;          // 200
    const int L = in_sizes[3];              // 50000
    const int D = 128;
    const int R = in_sizes[4] / D;          // 2000

    // Workspace: scores [B*R] f32, pref [B*D] f32, rid16 [L] u16
    size_t scores_b = (size_t)B * R * sizeof(float);
    size_t pref_b   = (size_t)B * D * sizeof(float);
    float* scores = (float*)d_ws;
    float* pref   = (float*)((char*)d_ws + scores_b);
    unsigned short* rid16 = (unsigned short*)((char*)d_ws + scores_b + pref_b);
    bool have_rid16 = ws_size >= scores_b + pref_b + (size_t)L * 2;

    // 1) user_pref
    pref_kernel<<<B, D, 0, stream>>>(user_seq, user_seq_len, poi_region_id,
                                     region_emb, pref, S, D);

    // 2) scores[B,R] (alpha folded in)
    dim3 g2((R + 255) / 256, B / 8);
    scores_kernel<<<g2, 256, 0, stream>>>(pref, region_emb, alpha, scores, R);

    // 2b) rid16 conversion
    if (have_rid16 && R <= MAX_R) {
        int nq = (L + 3) / 4;
        rid16_kernel<<<(nq + 255) / 256, 256, 0, stream>>>(poi_region_id, rid16, L);
    }

    // 3) output
    int L4 = L / 4;
    if (L4 > 0 && R <= MAX_R) {
        int CPB = (L4 + OUT_F - 1) / OUT_F;
        dim3 g3(OUT_F, B);
        if (have_rid16) {
            out_kernel_u16c<<<g3, OUT_BLOCK, 0, stream>>>(
                pred_base, scores, rid16, out, L4, L, R, CPB);
        } else {
            out_kernel_pipe<<<g3, OUT_BLOCK, 0, stream>>>(
                pred_base, scores, poi_region_id, out, L4, L, R, CPB);
        }
    } else if (L4 > 0) {
        dim3 gt(((L4 * 4) + 255) / 256, B);
        out_kernel_scalar<<<gt, 256, 0, stream>>>(
            pred_base, scores, poi_region_id, out, 0, L4 * 4, R);
    }
    int tail = L - L4 * 4;
    if (tail > 0) {
        dim3 gt(1, B);
        out_kernel_scalar<<<gt, 64, 0, stream>>>(pred_base, scores, poi_region_id,
                                                 out, L4 * 4, L, R);
    }
}

// Round 13
// 95.872 us; speedup vs baseline: 1.1786x; 1.0292x over previous
//
#include <hip/hip_runtime.h>

#define K_RECENT 10

typedef float f32x4 __attribute__((ext_vector_type(4)));
typedef int   i32x4 __attribute__((ext_vector_type(4)));

// ---------------------------------------------------------------------------
// Kernel 1: user_pref[b, :] = masked mean of region_emb over last-10 valid
// positions. One block per b, 128 threads (= D).
// ---------------------------------------------------------------------------
__global__ void pref_kernel(const int* __restrict__ user_seq,
                            const int* __restrict__ user_seq_len,
                            const int* __restrict__ poi_region_id,
                            const float* __restrict__ region_emb,
                            float* __restrict__ pref,
                            int S, int D) {
    int b = blockIdx.x;
    int tid = threadIdx.x;
    __shared__ int rids[K_RECENT];

    int len = user_seq_len[b];
    if (tid < K_RECENT) {
        int pos = len - K_RECENT + tid;
        int r = -1;
        if (pos >= 0) {
            int poi = user_seq[b * S + pos];
            r = poi_region_id[poi];
        }
        rids[tid] = r;
    }
    __syncthreads();

    float acc = 0.f;
    int cnt = 0;
#pragma unroll
    for (int j = 0; j < K_RECENT; ++j) {
        int r = rids[j];
        if (r >= 0) {
            ++cnt;
            acc += region_emb[r * D + tid];
        }
    }
    float c = (cnt > 0) ? (float)cnt : 1.f;
    pref[b * D + tid] = acc / c;
}

// ---------------------------------------------------------------------------
// Kernel 2 (proven BT=8): scores[b,r] = alpha * (pref[b] . region_emb[r])
// pref tile in LDS (block-uniform f32x4 broadcast reads -> ds_read_b128);
// region_emb (1 MB) L2-resident. alpha folded so out kernel is a pure add.
// ---------------------------------------------------------------------------
__global__ void scores_kernel(const float* __restrict__ pref,
                              const float* __restrict__ region_emb,
                              const float* __restrict__ alpha_p,
                              float* __restrict__ scores,
                              int R) {
    const int BT = 8;
    const int D  = 128;
    __shared__ float pl[BT * D];

    int tid = threadIdx.x;
    int b0  = blockIdx.y * BT;
    float alpha = alpha_p[0];

    ((f32x4*)pl)[tid] = ((const f32x4*)(pref + (size_t)b0 * D))[tid];
    __syncthreads();

    int r = blockIdx.x * blockDim.x + tid;
    if (r >= R) return;

    float acc[BT];
#pragma unroll
    for (int bb = 0; bb < BT; ++bb) acc[bb] = 0.f;

    const f32x4* erow = (const f32x4*)(region_emb + (size_t)r * D);
#pragma unroll 8
    for (int d4 = 0; d4 < D / 4; ++d4) {
        f32x4 e = erow[d4];
#pragma unroll
        for (int bb = 0; bb < BT; ++bb) {
            f32x4 pv = *reinterpret_cast<const f32x4*>(&pl[bb * D + d4 * 4]);
            acc[bb] = fmaf(e.x, pv.x,
                      fmaf(e.y, pv.y,
                      fmaf(e.z, pv.z,
                      fmaf(e.w, pv.w, acc[bb]))));
        }
    }
#pragma unroll
    for (int bb = 0; bb < BT; ++bb)
        scores[(size_t)(b0 + bb) * R + r] = acc[bb] * alpha;
}

// ---------------------------------------------------------------------------
// Kernel 3 (proven round-8): out[b,l] = pred[b,l] + srow[rid[l]]
// Score row in LDS (LDS gather mandatory: global gather +28 us).
// Nontemporal stores mandatory (plain stores evict pred/rid from L2/L3,
// +22 us — round-9 A/B). PIPE=4 register batching; blended-stream
// saturated at ~8 TB/s aggregate (occupancy/MLP/path/index-width all
// proven neutral, rounds 5-12).
// ---------------------------------------------------------------------------
#define OUT_BLOCK   256
#define OUT_F       4
#define PIPE        4
#define MAX_R       2048

__global__ void out_kernel_pipe(const float* __restrict__ pred,
                                const float* __restrict__ scores,
                                const int* __restrict__ rid,
                                float* __restrict__ out,
                                int L4, int L, int R, int CPB) {
    __shared__ float srow[MAX_R];
    int b   = blockIdx.y;
    int tid = threadIdx.x;

    const float* g = scores + (size_t)b * R;
    int R4 = R >> 2;
    for (int i = tid; i < R4; i += OUT_BLOCK)
        ((f32x4*)srow)[i] = ((const f32x4*)g)[i];
    for (int i = (R4 << 2) + tid; i < R; i += OUT_BLOCK)
        srow[i] = g[i];
    __syncthreads();

    int base = blockIdx.x * CPB;
    int n = min(CPB, L4 - base);
    if (n <= 0) return;

    const i32x4* rp = (const i32x4*)rid + base;
    const f32x4* pp = (const f32x4*)(pred + (size_t)b * L) + base;
    f32x4*       op = (f32x4*)(out + (size_t)b * L) + base;

    int rounds  = n >> 8;
    int batches = rounds / PIPE;

    for (int kb = 0; kb < batches; ++kb) {
        int i0 = kb * (PIPE * OUT_BLOCK) + tid;
        i32x4 r4v[PIPE];
        f32x4 p[PIPE];
#pragma unroll
        for (int j = 0; j < PIPE; ++j) r4v[j] = rp[i0 + j * OUT_BLOCK];
#pragma unroll
        for (int j = 0; j < PIPE; ++j) p[j]  = pp[i0 + j * OUT_BLOCK];
#pragma unroll
        for (int j = 0; j < PIPE; ++j) {
            f32x4 o;
            o.x = p[j].x + srow[r4v[j].x];
            o.y = p[j].y + srow[r4v[j].y];
            o.z = p[j].z + srow[r4v[j].z];
            o.w = p[j].w + srow[r4v[j].w];
            __builtin_nontemporal_store(o, &op[i0 + j * OUT_BLOCK]);
        }
    }
    for (int k = batches * PIPE; k < rounds; ++k) {
        int i = k * OUT_BLOCK + tid;
        i32x4 c = rp[i];
        f32x4 p = pp[i];
        f32x4 o;
        o.x = p.x + srow[c.x];
        o.y = p.y + srow[c.y];
        o.z = p.z + srow[c.z];
        o.w = p.w + srow[c.w];
        __builtin_nontemporal_store(o, &op[i]);
    }
    int i = rounds * OUT_BLOCK + tid;
    if (i < n) {
        i32x4 c = rp[i];
        f32x4 p = pp[i];
        f32x4 o;
        o.x = p.x + srow[c.x];
        o.y = p.y + srow[c.y];
        o.z = p.z + srow[c.z];
        o.w = p.w + srow[c.w];
        __builtin_nontemporal_store(o, &op[i]);
    }
}

// Fallback: direct L1 gather (R > MAX_R, or ragged tail). scores pre-scaled.
__global__ void out_kernel_scalar(const float* __restrict__ pred,
                                  const float* __restrict__ scores,
                                  const int* __restrict__ rid,
                                  float* __restrict__ out,
                                  int l0, int L, int R) {
    int b = blockIdx.y;
    int l = l0 + blockIdx.x * blockDim.x + threadIdx.x;
    if (l >= L) return;
    out[(size_t)b * L + l] =
        pred[(size_t)b * L + l] + scores[(size_t)b * R + rid[l]];
}

// Generic scores fallback (any B remainder), BT=1.
__global__ void scores_kernel_b1(const float* __restrict__ pref,
                                 const float* __restrict__ region_emb,
                                 const float* __restrict__ alpha_p,
                                 float* __restrict__ scores,
                                 int R, int b) {
    int r = blockIdx.x * blockDim.x + threadIdx.x;
    if (r >= R) return;
    float alpha = alpha_p[0];
    const f32x4* erow = (const f32x4*)(region_emb + (size_t)r * 128);
    const f32x4* pr   = (const f32x4*)(pref + (size_t)b * 128);
    float acc = 0.f;
#pragma unroll
    for (int d4 = 0; d4 < 32; ++d4) {
        f32x4 e = erow[d4], p = pr[d4];
        acc = fmaf(e.x, p.x, fmaf(e.y, p.y, fmaf(e.z, p.z, fmaf(e.w, p.w, acc))));
    }
    scores[(size_t)b * R + r] = acc * alpha;
}

extern "C" void kernel_launch(void* const* d_in, const int* in_sizes, int n_in,
                              void* d_out, int out_size, void* d_ws, size_t ws_size,
                              hipStream_t stream) {
    const float* pred_base     = (const float*)d_in[0];
    const int*   user_seq      = (const int*)d_in[1];
    const int*   user_seq_len  = (const int*)d_in[2];
    const int*   poi_region_id = (const int*)d_in[3];
    const float* region_emb    = (const float*)d_in[4];
    const float* alpha         = (const float*)d_in[5];
    float*       out           = (float*)d_out;

    const int B = in_sizes[2];              // 1024
    const int S = in_sizes[1] / B;          // 200
    const int L = in_sizes[3];              // 50000
    const int D = 128;
    const int R = in_sizes[4] / D;          // 2000

    // Workspace layout: scores [B*R] f32, pref [B*D] f32  (~8.7 MB total)
    float* scores = (float*)d_ws;
    float* pref   = scores + (size_t)B * R;

    // 1) user_pref
    pref_kernel<<<B, D, 0, stream>>>(user_seq, user_seq_len, poi_region_id,
                                     region_emb, pref, S, D);

    // 2) scores[B,R] (alpha folded in), BT=8 main + BT=1 remainder
    int bmain = (B / 8) * 8;
    if (bmain > 0) {
        dim3 g2((R + 255) / 256, bmain / 8);
        scores_kernel<<<g2, 256, 0, stream>>>(pref, region_emb, alpha, scores, R);
    }
    for (int b = bmain; b < B; ++b)
        scores_kernel_b1<<<(R + 255) / 256, 256, 0, stream>>>(
            pref, region_emb, alpha, scores, R, b);

    // 3) output
    int L4 = L / 4;
    if (L4 > 0) {
        if (R <= MAX_R) {
            int CPB = (L4 + OUT_F - 1) / OUT_F;
            dim3 g3(OUT_F, B);
            out_kernel_pipe<<<g3, OUT_BLOCK, 0, stream>>>(
                pred_base, scores, poi_region_id, out, L4, L, R, CPB);
        } else {
            dim3 gt(((L4 * 4) + 255) / 256, B);
            out_kernel_scalar<<<gt, 256, 0, stream>>>(
                pred_base, scores, poi_region_id, out, 0, L4 * 4, R);
        }
    }
    int tail = L - L4 * 4;
    if (tail > 0) {
        dim3 gt(1, B);
        out_kernel_scalar<<<gt, 64, 0, stream>>>(pred_base, scores, poi_region_id,
                                                 out, L4 * 4, L, R);
    }
}